// Round 1
// baseline (606.425 us; speedup 1.0000x reference)
//
#include <hip/hip_runtime.h>
#include <hip/hip_bf16.h>

#define BATCH 32
#define NNODE 2048
#define NEDGE 8192
#define DIM   512
#define NREL  8
#define VG    50000
#define VS    25000
#define ZI    4608           // 512 (root) + 8*512 (basis)
#define NCH   36             // 4608 / 128 i-chunks
#define GBLK  1563           // ceil(50000/32)
#define SBLK  782            // ceil(25000/32)
#define PG    25             // lse chunks for global head (2048 each)
#define PS    13             // lse chunks for sense head

// ---------------------------------------------------------------------------
// K1: per-batch edge scan (dst==0 only), builds z[g][0..4607]:
//   z[g][0..511]        = x[g,0,:]
//   z[g][512+b*512+i]   = y[g,b,i] = sum_r comp[r,b] * vsum[g,r,i]/max(cnt,1)
// Deterministic: matched edges processed in global e-order, no atomics.
// ---------------------------------------------------------------------------
__global__ __launch_bounds__(512) void k_conv(const float* __restrict__ x,
                                              const int* __restrict__ ei,
                                              const int* __restrict__ et,
                                              const float* __restrict__ comp,
                                              float* __restrict__ z) {
    int g = blockIdx.x;
    int t = threadIdx.x;
    int wv = t >> 6, lane = t & 63;
    __shared__ int elds[8 * 128];
    __shared__ int wcnt[8];
    const int* srcp = ei + (size_t)(g * 2 + 0) * NEDGE;
    const int* dstp = ei + (size_t)(g * 2 + 1) * NEDGE;

    // phase 1: each wave compacts its contiguous 1024-edge chunk (order kept)
    int run = 0;
    for (int it = 0; it < 16; it++) {
        int e = wv * 1024 + it * 64 + lane;
        bool m = (dstp[e] == 0);
        unsigned long long mask = __ballot(m);
        int rank = __popcll(mask & ((1ull << lane) - 1ull));
        if (m && (run + rank) < 128) elds[wv * 128 + run + rank] = e;
        run += (int)__popcll(mask);
    }
    if (lane == 0) wcnt[wv] = (run > 128) ? 128 : run;
    __syncthreads();

    // phase 2: every thread owns one d; accumulate per-relation sums in regs
    int d = t;  // 512 threads = DIM
    float s0=0,s1=0,s2=0,s3=0,s4=0,s5=0,s6=0,s7=0;
    int   c0=0,c1=0,c2=0,c3=0,c4=0,c5=0,c6=0,c7=0;
    for (int w = 0; w < 8; w++) {
        int cw = wcnt[w];
        for (int i = 0; i < cw; i++) {
            int e = elds[w * 128 + i];
            int r = et[(size_t)g * NEDGE + e];
            int sn = srcp[e];
            float val = x[((size_t)g * NNODE + sn) * DIM + d];
            if (r == 0) { s0 += val; c0++; }
            if (r == 1) { s1 += val; c1++; }
            if (r == 2) { s2 += val; c2++; }
            if (r == 3) { s3 += val; c3++; }
            if (r == 4) { s4 += val; c4++; }
            if (r == 5) { s5 += val; c5++; }
            if (r == 6) { s6 += val; c6++; }
            if (r == 7) { s7 += val; c7++; }
        }
    }
    float sv[8] = {s0,s1,s2,s3,s4,s5,s6,s7};
    float inv[8];
    int   cv[8] = {c0,c1,c2,c3,c4,c5,c6,c7};
    #pragma unroll
    for (int r = 0; r < 8; r++) inv[r] = 1.0f / fmaxf((float)cv[r], 1.0f);

    z[(size_t)g * ZI + d] = x[((size_t)g * NNODE + 0) * DIM + d];
    #pragma unroll
    for (int b = 0; b < 8; b++) {
        float y = 0.f;
        #pragma unroll
        for (int r = 0; r < 8; r++) y += comp[r * 8 + b] * inv[r] * sv[r];
        z[(size_t)g * ZI + 512 + b * 512 + d] = y;
    }
}

// ---------------------------------------------------------------------------
// K2a: partial GEMM  part2[c][g][d] = sum_{i in chunk c} z[g][i] * M[i][d]
// M = [root ; basis_flat], chunks of 128 i, d-tiles of 128. 144 blocks.
// ---------------------------------------------------------------------------
__global__ __launch_bounds__(512) void k_gemm_part(const float* __restrict__ z,
                                                   const float* __restrict__ root,
                                                   const float* __restrict__ basis,
                                                   float* __restrict__ part2) {
    int bx = blockIdx.x;
    int dt = bx & 3;       // d-tile 0..3
    int cc = bx >> 2;      // i-chunk 0..35
    int t = threadIdx.x;
    int dl = t & 127, gq = t >> 7;  // gq 0..3 -> 8 g each
    __shared__ float ztT[128][33];
    #pragma unroll
    for (int rep = 0; rep < 8; rep++) {
        int flat = rep * 512 + t;           // 4096 elems
        int g = flat >> 7, i = flat & 127;  // coalesced within each g-row
        ztT[i][g] = 0.f;                    // placeholder, fixed below
        // actually need g in 0..31: flat>>7 gives 0..31 over 8 reps ✓
        ztT[i][g] = z[(size_t)g * ZI + cc * 128 + i];
    }
    __syncthreads();
    const float* M = (cc < 4) ? (root + (size_t)(cc * 128) * 512)
                              : (basis + (size_t)((cc - 4) * 128) * 512);
    float acc[8] = {0,0,0,0,0,0,0,0};
    for (int i = 0; i < 128; i++) {
        float m = M[(size_t)i * 512 + dt * 128 + dl];
        #pragma unroll
        for (int j = 0; j < 8; j++) acc[j] += ztT[i][gq * 8 + j] * m;
    }
    #pragma unroll
    for (int j = 0; j < 8; j++) {
        int g = gq * 8 + j;
        part2[((size_t)cc * 32 + g) * 512 + dt * 128 + dl] = acc[j];
    }
}

// ---------------------------------------------------------------------------
// K2b: h0[g][d] = relu(bias_conv[d] + sum_c part2[c][g][d]); pack bf16 pairs
// h0t layout: [kp in 0..255][g in 0..31] as uint (lo=even k, hi=odd k)
// ---------------------------------------------------------------------------
__device__ __forceinline__ unsigned bf16rne(float f) {
    unsigned u = __float_as_uint(f);
    return (u + 0x7FFFu + ((u >> 16) & 1u)) >> 16;
}

__global__ __launch_bounds__(256) void k_h0(const float* __restrict__ part2,
                                            const float* __restrict__ bias_conv,
                                            unsigned* __restrict__ h0t) {
    int g = blockIdx.x;
    int p = threadIdx.x;          // pair index 0..255
    int d0 = 2 * p;
    float v0 = bias_conv[d0], v1 = bias_conv[d0 + 1];
    for (int cc = 0; cc < NCH; cc++) {
        const float* pp = part2 + ((size_t)cc * 32 + g) * 512 + d0;
        v0 += pp[0];
        v1 += pp[1];
    }
    v0 = fmaxf(v0, 0.f);
    v1 = fmaxf(v1, 0.f);
    h0t[p * 32 + g] = bf16rne(v0) | (bf16rne(v1) << 16);
}

// ---------------------------------------------------------------------------
// K3: logits[g][v] = bias[v] + dot(h0[g], w[v]).  The 153.6MB streaming kernel.
// Block: 256 thr, 32 vocab rows, all 32 batches. h0 (bf16-packed) in 32KB LDS.
// Thread: g = t>>3, 4 consecutive vocab rows per thread. w read exactly once.
// ---------------------------------------------------------------------------
__global__ __launch_bounds__(256) void k_logits(const unsigned* __restrict__ h0t,
                                                const float* __restrict__ wg,
                                                const float* __restrict__ bg,
                                                const float* __restrict__ wsn,
                                                const float* __restrict__ bsv,
                                                float* __restrict__ out) {
    __shared__ unsigned hl[8192];  // 32KB: [kp][g]
    int t = threadIdx.x;
    #pragma unroll
    for (int rep = 0; rep < 32; rep++) hl[rep * 256 + t] = h0t[rep * 256 + t];
    __syncthreads();

    int bx = blockIdx.x;
    const float* w; const float* bias; float* ob; int V; int v0;
    if (bx < GBLK) { w = wg;  bias = bg;  ob = out;                     V = VG; v0 = bx * 32; }
    else           { w = wsn; bias = bsv; ob = out + (size_t)BATCH * VG; V = VS; v0 = (bx - GBLK) * 32; }

    int g = t >> 3, vq = t & 7;
    int vb = v0 + vq * 4;
    const float* wr0 = w + (size_t)((vb + 0 < V) ? vb + 0 : V - 1) * 512;
    const float* wr1 = w + (size_t)((vb + 1 < V) ? vb + 1 : V - 1) * 512;
    const float* wr2 = w + (size_t)((vb + 2 < V) ? vb + 2 : V - 1) * 512;
    const float* wr3 = w + (size_t)((vb + 3 < V) ? vb + 3 : V - 1) * 512;
    float acc0 = 0.f, acc1 = 0.f, acc2 = 0.f, acc3 = 0.f;

    #pragma unroll 4
    for (int kp = 0; kp < 256; kp += 2) {
        unsigned ha = hl[kp * 32 + g];
        unsigned hb = hl[kp * 32 + 32 + g];
        float f0 = __uint_as_float(ha << 16);
        float f1 = __uint_as_float(ha & 0xFFFF0000u);
        float f2 = __uint_as_float(hb << 16);
        float f3 = __uint_as_float(hb & 0xFFFF0000u);
        int k = kp * 2;
        float4 a = *(const float4*)(wr0 + k);
        float4 b = *(const float4*)(wr1 + k);
        float4 c = *(const float4*)(wr2 + k);
        float4 d = *(const float4*)(wr3 + k);
        acc0 += a.x * f0 + a.y * f1 + a.z * f2 + a.w * f3;
        acc1 += b.x * f0 + b.y * f1 + b.z * f2 + b.w * f3;
        acc2 += c.x * f0 + c.y * f1 + c.z * f2 + c.w * f3;
        acc3 += d.x * f0 + d.y * f1 + d.z * f2 + d.w * f3;
    }
    if (vb + 0 < V) acc0 += bias[vb + 0];
    if (vb + 1 < V) acc1 += bias[vb + 1];
    if (vb + 2 < V) acc2 += bias[vb + 2];
    if (vb + 3 < V) acc3 += bias[vb + 3];

    size_t obase = (size_t)g * V + vb;
    if (vb + 4 <= V) {
        float4 o; o.x = acc0; o.y = acc1; o.z = acc2; o.w = acc3;
        *(float4*)(ob + obase) = o;
    } else {
        if (vb + 0 < V) ob[obase + 0] = acc0;
        if (vb + 1 < V) ob[obase + 1] = acc1;
        if (vb + 2 < V) ob[obase + 2] = acc2;
        if (vb + 3 < V) ob[obase + 3] = acc3;
    }
}

// ---------------------------------------------------------------------------
// K4a: partial exp-sums per (head,g,chunk-of-2048). Deterministic tree reduce.
// ---------------------------------------------------------------------------
__global__ __launch_bounds__(256) void k_lse_part(const float* __restrict__ out,
                                                  float* __restrict__ part) {
    int bx = blockIdx.x;
    int V, ci, pidx;
    const float* row;
    if (bx < 32 * PG) {
        int g = bx / PG; ci = bx % PG; V = VG;
        row = out + (size_t)g * VG;
        pidx = g * PG + ci;
    } else {
        int b2 = bx - 32 * PG;
        int g = b2 / PS; ci = b2 % PS; V = VS;
        row = out + (size_t)BATCH * VG + (size_t)g * VS;
        pidx = 32 * PG + g * PS + ci;
    }
    int t = threadIdx.x;
    float p = 0.f;
    int base = ci * 2048 + t * 8;
    #pragma unroll
    for (int jj = 0; jj < 8; jj++) {
        int idx = base + jj;
        if (idx < V) p += expf(row[idx]);
    }
    #pragma unroll
    for (int s = 1; s < 64; s <<= 1) p += __shfl_xor(p, s);
    __shared__ float wsum[4];
    if ((t & 63) == 0) wsum[t >> 6] = p;
    __syncthreads();
    if (t == 0) part[pidx] = wsum[0] + wsum[1] + wsum[2] + wsum[3];
}

__global__ __launch_bounds__(64) void k_lse_final(const float* __restrict__ part,
                                                  float* __restrict__ lse) {
    int t = threadIdx.x;  // 64 threads: head = t>>5, g = t&31
    int head = t >> 5, g = t & 31;
    float s = 0.f;
    if (head == 0) { for (int c = 0; c < PG; c++) s += part[g * PG + c]; }
    else           { for (int c = 0; c < PS; c++) s += part[32 * PG + g * PS + c]; }
    lse[t] = logf(s);
}

__global__ __launch_bounds__(256) void k_sub(float* __restrict__ out,
                                             const float* __restrict__ lse) {
    unsigned i4 = blockIdx.x * 256u + threadIdx.x;
    if (i4 >= 600000u) return;
    unsigned idx = i4 * 4u;
    float l;
    if (idx < 1600000u) l = lse[idx / 50000u];
    else                l = lse[32u + (idx - 1600000u) / 25000u];
    float4 v = *(float4*)(out + idx);
    v.x -= l; v.y -= l; v.z -= l; v.w -= l;
    *(float4*)(out + idx) = v;
}

// ---------------------------------------------------------------------------
extern "C" void kernel_launch(void* const* d_in, const int* in_sizes, int n_in,
                              void* d_out, int out_size, void* d_ws, size_t ws_size,
                              hipStream_t stream) {
    const float* x        = (const float*)d_in[0];
    const int*   ei       = (const int*)  d_in[1];
    const int*   et       = (const int*)  d_in[2];
    const float* basis    = (const float*)d_in[3];
    const float* comp     = (const float*)d_in[4];
    const float* root     = (const float*)d_in[5];
    const float* biasc    = (const float*)d_in[6];
    const float* wg       = (const float*)d_in[7];
    const float* bg       = (const float*)d_in[8];
    const float* wsn      = (const float*)d_in[9];
    const float* bsv      = (const float*)d_in[10];
    float* out = (float*)d_out;

    // Big scratch lives in d_out (consumed before k_logits overwrites it):
    //   z:     out[0 .. 147456)                (32 x 4608)
    //   part2: out[147456 .. 737280)           (36 x 32 x 512)
    float* z     = out;
    float* part2 = out + (size_t)BATCH * ZI;
    // Small scratch in ws (must survive k_logits):
    unsigned* h0t  = (unsigned*)d_ws;            // 8192 uints = 32KB
    float*    plse = (float*)d_ws + 8192;        // 32*PG + 32*PS = 1216
    float*    lse  = plse + 32 * PG + 32 * PS;   // 64

    k_conv     <<<BATCH, 512, 0, stream>>>(x, ei, et, comp, z);
    k_gemm_part<<<NCH * 4, 512, 0, stream>>>(z, root, basis, part2);
    k_h0       <<<BATCH, 256, 0, stream>>>(part2, biasc, h0t);
    k_logits   <<<GBLK + SBLK, 256, 0, stream>>>(h0t, wg, bg, wsn, bsv, out);
    k_lse_part <<<32 * PG + 32 * PS, 256, 0, stream>>>(out, plse);
    k_lse_final<<<1, 64, 0, stream>>>(plse, lse);
    k_sub      <<<2344, 256, 0, stream>>>(out, lse);
}

// Round 2
// 119.754 us; speedup vs baseline: 5.0639x; 5.0639x over previous
//
#include <hip/hip_runtime.h>
#include <hip/hip_bf16.h>

#define BATCH 32
#define NNODE 2048
#define NEDGE 8192
#define DIM   512
#define NREL  8
#define VG    50000
#define VS    25000
#define ZI    4608           // 512 (root) + 8*512 (basis)
#define NCH   36             // 4608 / 128 i-chunks
#define GBLK  1563           // ceil(50000/32)
#define SBLK  782            // ceil(25000/32)
#define PG    25             // lse chunks for global head (2048 each)
#define PS    13             // lse chunks for sense head

// ---------------------------------------------------------------------------
// K1: per-batch edge scan (dst==0 only), builds z[g][0..4607]
// ---------------------------------------------------------------------------
__global__ __launch_bounds__(512) void k_conv(const float* __restrict__ x,
                                              const int* __restrict__ ei,
                                              const int* __restrict__ et,
                                              const float* __restrict__ comp,
                                              float* __restrict__ z) {
    int g = blockIdx.x;
    int t = threadIdx.x;
    int wv = t >> 6, lane = t & 63;
    __shared__ int elds[8 * 128];
    __shared__ int wcnt[8];
    const int* srcp = ei + (size_t)(g * 2 + 0) * NEDGE;
    const int* dstp = ei + (size_t)(g * 2 + 1) * NEDGE;

    int run = 0;
    for (int it = 0; it < 16; it++) {
        int e = wv * 1024 + it * 64 + lane;
        bool m = (dstp[e] == 0);
        unsigned long long mask = __ballot(m);
        int rank = __popcll(mask & ((1ull << lane) - 1ull));
        if (m && (run + rank) < 128) elds[wv * 128 + run + rank] = e;
        run += (int)__popcll(mask);
    }
    if (lane == 0) wcnt[wv] = (run > 128) ? 128 : run;
    __syncthreads();

    int d = t;
    float s0=0,s1=0,s2=0,s3=0,s4=0,s5=0,s6=0,s7=0;
    int   c0=0,c1=0,c2=0,c3=0,c4=0,c5=0,c6=0,c7=0;
    for (int w = 0; w < 8; w++) {
        int cw = wcnt[w];
        for (int i = 0; i < cw; i++) {
            int e = elds[w * 128 + i];
            int r = et[(size_t)g * NEDGE + e];
            int sn = srcp[e];
            float val = x[((size_t)g * NNODE + sn) * DIM + d];
            if (r == 0) { s0 += val; c0++; }
            if (r == 1) { s1 += val; c1++; }
            if (r == 2) { s2 += val; c2++; }
            if (r == 3) { s3 += val; c3++; }
            if (r == 4) { s4 += val; c4++; }
            if (r == 5) { s5 += val; c5++; }
            if (r == 6) { s6 += val; c6++; }
            if (r == 7) { s7 += val; c7++; }
        }
    }
    float sv[8] = {s0,s1,s2,s3,s4,s5,s6,s7};
    float inv[8];
    int   cv[8] = {c0,c1,c2,c3,c4,c5,c6,c7};
    #pragma unroll
    for (int r = 0; r < 8; r++) inv[r] = 1.0f / fmaxf((float)cv[r], 1.0f);

    z[(size_t)g * ZI + d] = x[((size_t)g * NNODE + 0) * DIM + d];
    #pragma unroll
    for (int b = 0; b < 8; b++) {
        float y = 0.f;
        #pragma unroll
        for (int r = 0; r < 8; r++) y += comp[r * 8 + b] * inv[r] * sv[r];
        z[(size_t)g * ZI + 512 + b * 512 + d] = y;
    }
}

// ---------------------------------------------------------------------------
// K2a: partial GEMM  part2[c][g][d] = sum_{i in chunk c} z[g][i] * M[i][d]
// ---------------------------------------------------------------------------
__global__ __launch_bounds__(512) void k_gemm_part(const float* __restrict__ z,
                                                   const float* __restrict__ root,
                                                   const float* __restrict__ basis,
                                                   float* __restrict__ part2) {
    int bx = blockIdx.x;
    int dt = bx & 3;
    int cc = bx >> 2;
    int t = threadIdx.x;
    int dl = t & 127, gq = t >> 7;
    __shared__ float ztT[128][33];
    #pragma unroll
    for (int rep = 0; rep < 8; rep++) {
        int flat = rep * 512 + t;
        int g = flat >> 7, i = flat & 127;
        ztT[i][g] = z[(size_t)g * ZI + cc * 128 + i];
    }
    __syncthreads();
    const float* M = (cc < 4) ? (root + (size_t)(cc * 128) * 512)
                              : (basis + (size_t)((cc - 4) * 128) * 512);
    float acc[8] = {0,0,0,0,0,0,0,0};
    for (int i = 0; i < 128; i++) {
        float m = M[(size_t)i * 512 + dt * 128 + dl];
        #pragma unroll
        for (int j = 0; j < 8; j++) acc[j] += ztT[i][gq * 8 + j] * m;
    }
    #pragma unroll
    for (int j = 0; j < 8; j++) {
        int g = gq * 8 + j;
        part2[((size_t)cc * 32 + g) * 512 + dt * 128 + dl] = acc[j];
    }
}

// ---------------------------------------------------------------------------
// K2b: h0 reduce + relu + pack bf16 pairs.
// NEW layout for k_logits2: flat uint index = kp*32 + (g&15)*2 + (g>>4)
//   i.e. uint2 element [kp][gq] = { pack(g=gq, kp), pack(g=gq+16, kp) }
// ---------------------------------------------------------------------------
__device__ __forceinline__ unsigned bf16rne(float f) {
    unsigned u = __float_as_uint(f);
    return (u + 0x7FFFu + ((u >> 16) & 1u)) >> 16;
}

__global__ __launch_bounds__(256) void k_h0(const float* __restrict__ part2,
                                            const float* __restrict__ bias_conv,
                                            unsigned* __restrict__ h0t) {
    int g = blockIdx.x;
    int p = threadIdx.x;          // pair index kp = 0..255
    int d0 = 2 * p;
    float v0 = bias_conv[d0], v1 = bias_conv[d0 + 1];
    for (int cc = 0; cc < NCH; cc++) {
        const float* pp = part2 + ((size_t)cc * 32 + g) * 512 + d0;
        v0 += pp[0];
        v1 += pp[1];
    }
    v0 = fmaxf(v0, 0.f);
    v1 = fmaxf(v1, 0.f);
    h0t[p * 32 + (g & 15) * 2 + (g >> 4)] = bf16rne(v0) | (bf16rne(v1) << 16);
}

// ---------------------------------------------------------------------------
// K3 (rewritten): logits[g][v] = bias[v] + dot(h0[g], w[v]).
// LDS-staged W: 32-row x 64-k chunks (8KB), double buffered, loaded via
// global_load_lds(width16) with XOR-swizzled granules (swz on src + on LDS
// read -> contiguous 1KB/instr global reads AND bank-conflict-free compute).
// Thread tile: 2 batches (gq, gq+16) x 2 rows (2rq, 2rq+1).
// LDS: 32KB h0 + 2x8KB W = 48KB -> 3 blocks/CU.
// ---------------------------------------------------------------------------
__device__ __forceinline__ void gload_lds16(const float* gsrc, float* ldst) {
    __builtin_amdgcn_global_load_lds(
        (const __attribute__((address_space(1))) void*)gsrc,
        (__attribute__((address_space(3))) void*)ldst,
        16, 0, 0);
}

__global__ __launch_bounds__(256) void k_logits2(const unsigned* __restrict__ h0t,
                                                 const float* __restrict__ wg,
                                                 const float* __restrict__ bg,
                                                 const float* __restrict__ wsn,
                                                 const float* __restrict__ bsv,
                                                 float* __restrict__ out) {
    __shared__ unsigned hl[8192];       // 32KB  [kp][gq] uint2-packed
    __shared__ float wbuf[2][2048];     // 2 x 8KB  [row 0..31][kq 0..15][4]

    int t = threadIdx.x;
    int bx = blockIdx.x;

    const float* w; const float* bias; float* ob; int V; int v0;
    if (bx < GBLK) { w = wg;  bias = bg;  ob = out;                     V = VG; v0 = bx * 32; }
    else           { w = wsn; bias = bsv; ob = out + (size_t)BATCH * VG; V = VS; v0 = (bx - GBLK) * 32; }
    int Vm1 = V - 1;

    int wv = t >> 6, l = t & 63;        // wave id, lane

    // --- stage chunk 0 into buf 0 (and h0 into LDS) ---
    {
        #pragma unroll
        for (int i = 0; i < 2; i++) {
            int o   = wv * 128 + i * 64 + l;       // granule 0..511
            int row = o >> 4;
            int kq  = o & 15;
            int vgr = v0 + row; if (vgr > Vm1) vgr = Vm1;
            const float* src = w + (size_t)vgr * 512 + ((kq ^ (row & 7)) << 2);
            gload_lds16(src, &wbuf[0][(wv * 128 + i * 64) * 4]);
        }
        #pragma unroll
        for (int rep = 0; rep < 8; rep++) {
            *(uint4*)&hl[rep * 1024 + t * 4] = *(const uint4*)&h0t[rep * 1024 + t * 4];
        }
    }
    asm volatile("s_waitcnt vmcnt(0)" ::: "memory");
    __syncthreads();

    int gq = t & 15;          // batches gq, gq+16
    int rq = t >> 4;          // rows 2rq, 2rq+1 (tile-local)
    int r0 = 2 * rq, r1 = 2 * rq + 1;
    int sz0 = r0 & 7, sz1 = r1 & 7;
    const uint2* h2 = (const uint2*)hl;

    float acc00 = 0.f, acc01 = 0.f, acc10 = 0.f, acc11 = 0.f;
    int cur = 0;

    for (int c = 0; c < 8; c++) {
        if (c < 7) {  // prefetch next chunk into other buffer
            #pragma unroll
            for (int i = 0; i < 2; i++) {
                int o   = wv * 128 + i * 64 + l;
                int row = o >> 4;
                int kq  = o & 15;
                int vgr = v0 + row; if (vgr > Vm1) vgr = Vm1;
                const float* src = w + (size_t)vgr * 512 + (c + 1) * 64
                                     + ((kq ^ (row & 7)) << 2);
                gload_lds16(src, &wbuf[cur ^ 1][(wv * 128 + i * 64) * 4]);
            }
        }

        const float4* w4 = (const float4*)wbuf[cur];
        #pragma unroll
        for (int kq = 0; kq < 16; kq++) {
            float4 wa = w4[r0 * 16 + (kq ^ sz0)];
            float4 wb = w4[r1 * 16 + (kq ^ sz1)];
            uint2 ha = h2[(c * 32 + kq * 2) * 16 + gq];      // k+0,k+1
            uint2 hb = h2[(c * 32 + kq * 2 + 1) * 16 + gq];  // k+2,k+3
            float fa0 = __uint_as_float(ha.x << 16);
            float fa1 = __uint_as_float(ha.x & 0xFFFF0000u);
            float fb0 = __uint_as_float(hb.x << 16);
            float fb1 = __uint_as_float(hb.x & 0xFFFF0000u);
            float ga0 = __uint_as_float(ha.y << 16);
            float ga1 = __uint_as_float(ha.y & 0xFFFF0000u);
            float gb0 = __uint_as_float(hb.y << 16);
            float gb1 = __uint_as_float(hb.y & 0xFFFF0000u);
            acc00 += wa.x * fa0 + wa.y * fa1 + wa.z * fb0 + wa.w * fb1;
            acc01 += wb.x * fa0 + wb.y * fa1 + wb.z * fb0 + wb.w * fb1;
            acc10 += wa.x * ga0 + wa.y * ga1 + wa.z * gb0 + wa.w * gb1;
            acc11 += wb.x * ga0 + wb.y * ga1 + wb.z * gb0 + wb.w * gb1;
        }

        asm volatile("s_waitcnt vmcnt(0)" ::: "memory");
        __syncthreads();
        cur ^= 1;
    }

    int vA = v0 + r0, vB = v0 + r1;
    int g0 = gq, g1 = gq + 16;
    if (vA < V) {
        float b0 = bias[vA];
        ob[(size_t)g0 * V + vA] = acc00 + b0;
        ob[(size_t)g1 * V + vA] = acc10 + b0;
    }
    if (vB < V) {
        float b1 = bias[vB];
        ob[(size_t)g0 * V + vB] = acc01 + b1;
        ob[(size_t)g1 * V + vB] = acc11 + b1;
    }
}

// ---------------------------------------------------------------------------
// K4: log-softmax pieces (unchanged)
// ---------------------------------------------------------------------------
__global__ __launch_bounds__(256) void k_lse_part(const float* __restrict__ out,
                                                  float* __restrict__ part) {
    int bx = blockIdx.x;
    int V, ci, pidx;
    const float* row;
    if (bx < 32 * PG) {
        int g = bx / PG; ci = bx % PG; V = VG;
        row = out + (size_t)g * VG;
        pidx = g * PG + ci;
    } else {
        int b2 = bx - 32 * PG;
        int g = b2 / PS; ci = b2 % PS; V = VS;
        row = out + (size_t)BATCH * VG + (size_t)g * VS;
        pidx = 32 * PG + g * PS + ci;
    }
    int t = threadIdx.x;
    float p = 0.f;
    int base = ci * 2048 + t * 8;
    #pragma unroll
    for (int jj = 0; jj < 8; jj++) {
        int idx = base + jj;
        if (idx < V) p += expf(row[idx]);
    }
    #pragma unroll
    for (int s = 1; s < 64; s <<= 1) p += __shfl_xor(p, s);
    __shared__ float wsum[4];
    if ((t & 63) == 0) wsum[t >> 6] = p;
    __syncthreads();
    if (t == 0) part[pidx] = wsum[0] + wsum[1] + wsum[2] + wsum[3];
}

__global__ __launch_bounds__(64) void k_lse_final(const float* __restrict__ part,
                                                  float* __restrict__ lse) {
    int t = threadIdx.x;
    int head = t >> 5, g = t & 31;
    float s = 0.f;
    if (head == 0) { for (int c = 0; c < PG; c++) s += part[g * PG + c]; }
    else           { for (int c = 0; c < PS; c++) s += part[32 * PG + g * PS + c]; }
    lse[t] = logf(s);
}

__global__ __launch_bounds__(256) void k_sub(float* __restrict__ out,
                                             const float* __restrict__ lse) {
    unsigned i4 = blockIdx.x * 256u + threadIdx.x;
    if (i4 >= 600000u) return;
    unsigned idx = i4 * 4u;
    float l;
    if (idx < 1600000u) l = lse[idx / 50000u];
    else                l = lse[32u + (idx - 1600000u) / 25000u];
    float4 v = *(float4*)(out + idx);
    v.x -= l; v.y -= l; v.z -= l; v.w -= l;
    *(float4*)(out + idx) = v;
}

// ---------------------------------------------------------------------------
extern "C" void kernel_launch(void* const* d_in, const int* in_sizes, int n_in,
                              void* d_out, int out_size, void* d_ws, size_t ws_size,
                              hipStream_t stream) {
    const float* x        = (const float*)d_in[0];
    const int*   ei       = (const int*)  d_in[1];
    const int*   et       = (const int*)  d_in[2];
    const float* basis    = (const float*)d_in[3];
    const float* comp     = (const float*)d_in[4];
    const float* root     = (const float*)d_in[5];
    const float* biasc    = (const float*)d_in[6];
    const float* wg       = (const float*)d_in[7];
    const float* bg       = (const float*)d_in[8];
    const float* wsn      = (const float*)d_in[9];
    const float* bsv      = (const float*)d_in[10];
    float* out = (float*)d_out;

    float* z     = out;
    float* part2 = out + (size_t)BATCH * ZI;
    unsigned* h0t  = (unsigned*)d_ws;            // 8192 uints = 32KB
    float*    plse = (float*)d_ws + 8192;
    float*    lse  = plse + 32 * PG + 32 * PS;

    k_conv     <<<BATCH, 512, 0, stream>>>(x, ei, et, comp, z);
    k_gemm_part<<<NCH * 4, 512, 0, stream>>>(z, root, basis, part2);
    k_h0       <<<BATCH, 256, 0, stream>>>(part2, biasc, h0t);
    k_logits2  <<<GBLK + SBLK, 256, 0, stream>>>(h0t, wg, bg, wsn, bsv, out);
    k_lse_part <<<32 * PG + 32 * PS, 256, 0, stream>>>(out, plse);
    k_lse_final<<<1, 64, 0, stream>>>(plse, lse);
    k_sub      <<<2344, 256, 0, stream>>>(out, lse);
}

// Round 3
// 82.818 us; speedup vs baseline: 7.3224x; 1.4460x over previous
//
#include <hip/hip_runtime.h>
#include <hip/hip_bf16.h>

#define BATCH 32
#define NNODE 2048
#define NEDGE 8192
#define DIM   512
#define NREL  8
#define VG    50000
#define VS    25000
#define ZI    4608           // 512 (root) + 8*512 (basis)
#define NCH   36             // 4608 / 128 i-chunks
#define GB3   391            // ceil(50000/128)
#define SB3   196            // ceil(25000/128)
#define PG    25             // lse chunks for global head (2048 each)
#define PS    13             // lse chunks for sense head

typedef __attribute__((ext_vector_type(4))) float f32x4;
typedef __attribute__((ext_vector_type(8))) short s16x8;

// ---------------------------------------------------------------------------
// K1: per-batch edge scan (dst==0 only), builds z[g][0..4607]
// ---------------------------------------------------------------------------
__global__ __launch_bounds__(512) void k_conv(const float* __restrict__ x,
                                              const int* __restrict__ ei,
                                              const int* __restrict__ et,
                                              const float* __restrict__ comp,
                                              float* __restrict__ z) {
    int g = blockIdx.x;
    int t = threadIdx.x;
    int wv = t >> 6, lane = t & 63;
    __shared__ int elds[8 * 128];
    __shared__ int wcnt[8];
    const int* srcp = ei + (size_t)(g * 2 + 0) * NEDGE;
    const int* dstp = ei + (size_t)(g * 2 + 1) * NEDGE;

    int run = 0;
    for (int it = 0; it < 16; it++) {
        int e = wv * 1024 + it * 64 + lane;
        bool m = (dstp[e] == 0);
        unsigned long long mask = __ballot(m);
        int rank = __popcll(mask & ((1ull << lane) - 1ull));
        if (m && (run + rank) < 128) elds[wv * 128 + run + rank] = e;
        run += (int)__popcll(mask);
    }
    if (lane == 0) wcnt[wv] = (run > 128) ? 128 : run;
    __syncthreads();

    int d = t;
    float s0=0,s1=0,s2=0,s3=0,s4=0,s5=0,s6=0,s7=0;
    int   c0=0,c1=0,c2=0,c3=0,c4=0,c5=0,c6=0,c7=0;
    for (int w = 0; w < 8; w++) {
        int cw = wcnt[w];
        for (int i = 0; i < cw; i++) {
            int e = elds[w * 128 + i];
            int r = et[(size_t)g * NEDGE + e];
            int sn = srcp[e];
            float val = x[((size_t)g * NNODE + sn) * DIM + d];
            if (r == 0) { s0 += val; c0++; }
            if (r == 1) { s1 += val; c1++; }
            if (r == 2) { s2 += val; c2++; }
            if (r == 3) { s3 += val; c3++; }
            if (r == 4) { s4 += val; c4++; }
            if (r == 5) { s5 += val; c5++; }
            if (r == 6) { s6 += val; c6++; }
            if (r == 7) { s7 += val; c7++; }
        }
    }
    float sv[8] = {s0,s1,s2,s3,s4,s5,s6,s7};
    float inv[8];
    int   cv[8] = {c0,c1,c2,c3,c4,c5,c6,c7};
    #pragma unroll
    for (int r = 0; r < 8; r++) inv[r] = 1.0f / fmaxf((float)cv[r], 1.0f);

    z[(size_t)g * ZI + d] = x[((size_t)g * NNODE + 0) * DIM + d];
    #pragma unroll
    for (int b = 0; b < 8; b++) {
        float y = 0.f;
        #pragma unroll
        for (int r = 0; r < 8; r++) y += comp[r * 8 + b] * inv[r] * sv[r];
        z[(size_t)g * ZI + 512 + b * 512 + d] = y;
    }
}

// ---------------------------------------------------------------------------
// K2a: partial GEMM  part2[c][g][d] = sum_{i in chunk c} z[g][i] * M[i][d]
// ---------------------------------------------------------------------------
__global__ __launch_bounds__(512) void k_gemm_part(const float* __restrict__ z,
                                                   const float* __restrict__ root,
                                                   const float* __restrict__ basis,
                                                   float* __restrict__ part2) {
    int bx = blockIdx.x;
    int dt = bx & 3;
    int cc = bx >> 2;
    int t = threadIdx.x;
    int dl = t & 127, gq = t >> 7;
    __shared__ float ztT[128][33];
    #pragma unroll
    for (int rep = 0; rep < 8; rep++) {
        int flat = rep * 512 + t;
        int g = flat >> 7, i = flat & 127;
        ztT[i][g] = z[(size_t)g * ZI + cc * 128 + i];
    }
    __syncthreads();
    const float* M = (cc < 4) ? (root + (size_t)(cc * 128) * 512)
                              : (basis + (size_t)((cc - 4) * 128) * 512);
    float acc[8] = {0,0,0,0,0,0,0,0};
    for (int i = 0; i < 128; i++) {
        float m = M[(size_t)i * 512 + dt * 128 + dl];
        #pragma unroll
        for (int j = 0; j < 8; j++) acc[j] += ztT[i][gq * 8 + j] * m;
    }
    #pragma unroll
    for (int j = 0; j < 8; j++) {
        int g = gq * 8 + j;
        part2[((size_t)cc * 32 + g) * 512 + dt * 128 + dl] = acc[j];
    }
}

// ---------------------------------------------------------------------------
// K2b: h0 reduce + relu + pack bf16 pairs.  h0t[g*256 + p] = bf16(2p)|bf16(2p+1)<<16
// ---------------------------------------------------------------------------
__device__ __forceinline__ unsigned bf16rne(float f) {
    unsigned u = __float_as_uint(f);
    return (u + 0x7FFFu + ((u >> 16) & 1u)) >> 16;
}

__global__ __launch_bounds__(256) void k_h0(const float* __restrict__ part2,
                                            const float* __restrict__ bias_conv,
                                            unsigned* __restrict__ h0t) {
    int g = blockIdx.x;
    int p = threadIdx.x;          // pair index kp = 0..255
    int d0 = 2 * p;
    float v0 = bias_conv[d0], v1 = bias_conv[d0 + 1];
    for (int cc = 0; cc < NCH; cc++) {
        const float* pp = part2 + ((size_t)cc * 32 + g) * 512 + d0;
        v0 += pp[0];
        v1 += pp[1];
    }
    v0 = fmaxf(v0, 0.f);
    v1 = fmaxf(v1, 0.f);
    h0t[g * 256 + p] = bf16rne(v0) | (bf16rne(v1) << 16);
}

// ---------------------------------------------------------------------------
// K3 (MFMA): logits[g][v] = bias[v] + dot(h0[g], w[v]).
// Pure streaming kernel. Block = 256 thr (4 waves), 128 vocab rows, 32 batches.
// W staged [128 rows][32 k] fp32 = 16KB chunks, double-buffered, via
// global_load_lds w=16 with 32B-granule XOR pre-swizzle on the SOURCE
// (LDS stays linear; read applies same XOR -> near-conflict-free ds_read_b128).
// h0 bf16 in LDS [32 g][512 k], 16B-granule XOR applied on ds_write side.
// Per wave: 2 n-tiles x 2 m-tiles, mfma_f32_16x16x32_bf16, W cvt fp32->bf16.
// LDS 64KB -> 2 blocks/CU.
// ---------------------------------------------------------------------------
__device__ __forceinline__ void gload_lds16(const float* gsrc, float* ldst) {
    __builtin_amdgcn_global_load_lds(
        (const __attribute__((address_space(1))) void*)gsrc,
        (__attribute__((address_space(3))) void*)ldst,
        16, 0, 0);
}

__device__ __forceinline__ short f2bf(float f) {
    __hip_bfloat16 h = __float2bfloat16(f);
    return *reinterpret_cast<short*>(&h);
}

__global__ __launch_bounds__(256) void k_logits3(const unsigned* __restrict__ h0t,
                                                 const float* __restrict__ wg,
                                                 const float* __restrict__ bg,
                                                 const float* __restrict__ wsn,
                                                 const float* __restrict__ bsv,
                                                 float* __restrict__ out) {
    __shared__ __align__(16) unsigned char hlds[32768];      // h0 [32][1024B], 16B-XOR
    __shared__ __align__(16) unsigned char wlds[2][16384];   // W [128][128B], 32B-XOR

    int t = threadIdx.x;
    int bx = blockIdx.x;
    int wv = t >> 6, l = t & 63;

    const float* w; const float* bias; float* ob; int V; int v0;
    if (bx < GB3) { w = wg;  bias = bg;  ob = out;                      V = VG; v0 = bx * 128; }
    else          { w = wsn; bias = bsv; ob = out + (size_t)BATCH * VG; V = VS; v0 = (bx - GB3) * 128; }
    int Vm1 = V - 1;

    // ---- h0 -> LDS (bf16, 16B-granule XOR by row) ----
    #pragma unroll
    for (int rep = 0; rep < 8; rep++) {
        int idx = rep * 256 + t;           // uint4 index, 2048 total
        int g = idx >> 6, q = idx & 63;    // q = 16B granule within 1KB row
        uint4 val = *(const uint4*)&h0t[idx * 4];
        *(uint4*)&hlds[g * 1024 + ((q << 4) ^ ((g & 7) << 4))] = val;
    }

    // ---- stage W chunk 0 ----
    #pragma unroll
    for (int i = 0; i < 4; i++) {
        int o = i * 256 + t;               // granule 0..1023
        int row = o >> 3, g16 = o & 7;
        int vr = v0 + row; if (vr > Vm1) vr = Vm1;
        const float* src = w + (size_t)vr * 512
                         + ((((g16 << 4) ^ ((row & 3) << 5))) >> 2);
        gload_lds16(src, (float*)&wlds[0][o * 16]);
    }
    asm volatile("s_waitcnt vmcnt(0)" ::: "memory");
    __syncthreads();

    f32x4 acc[2][2];
    #pragma unroll
    for (int a = 0; a < 2; a++)
        #pragma unroll
        for (int b = 0; b < 2; b++) acc[a][b] = (f32x4){0.f, 0.f, 0.f, 0.f};

    int g32 = l >> 4;                      // k-group 0..3
    int gl  = l & 15;
    int cur = 0;

    for (int kc = 0; kc < 16; kc++) {
        if (kc < 15) {                     // prefetch next chunk
            #pragma unroll
            for (int i = 0; i < 4; i++) {
                int o = i * 256 + t;
                int row = o >> 3, g16 = o & 7;
                int vr = v0 + row; if (vr > Vm1) vr = Vm1;
                const float* src = w + (size_t)vr * 512 + (kc + 1) * 32
                                 + ((((g16 << 4) ^ ((row & 3) << 5))) >> 2);
                gload_lds16(src, (float*)&wlds[cur ^ 1][o * 16]);
            }
        }

        // A fragments (both m-tiles share k-group)
        int abase = (kc * 64 + g32 * 16) ^ ((gl & 7) << 4);
        s16x8 a0 = *(const s16x8*)&hlds[gl * 1024 + abase];
        s16x8 a1 = *(const s16x8*)&hlds[(gl + 16) * 1024 + abase];

        #pragma unroll
        for (int ntl = 0; ntl < 2; ntl++) {
            int rloc = (wv * 2 + ntl) * 16 + gl;
            int boff = rloc * 128 + ((g32 * 32) ^ ((rloc & 3) << 5));
            float4 blo = *(const float4*)&wlds[cur][boff];
            float4 bhi = *(const float4*)&wlds[cur][boff + 16];
            s16x8 bf;
            bf[0] = f2bf(blo.x); bf[1] = f2bf(blo.y);
            bf[2] = f2bf(blo.z); bf[3] = f2bf(blo.w);
            bf[4] = f2bf(bhi.x); bf[5] = f2bf(bhi.y);
            bf[6] = f2bf(bhi.z); bf[7] = f2bf(bhi.w);
            acc[ntl][0] = __builtin_amdgcn_mfma_f32_16x16x32_bf16(a0, bf, acc[ntl][0], 0, 0, 0);
            acc[ntl][1] = __builtin_amdgcn_mfma_f32_16x16x32_bf16(a1, bf, acc[ntl][1], 0, 0, 0);
        }

        asm volatile("s_waitcnt vmcnt(0)" ::: "memory");
        __syncthreads();
        cur ^= 1;
    }

    // ---- epilogue: C/D layout col=lane&15, row=(lane>>4)*4+j ----
    int lrowb = (l >> 4) * 4;
    #pragma unroll
    for (int ntl = 0; ntl < 2; ntl++) {
        int vv = v0 + (wv * 2 + ntl) * 16 + gl;
        if (vv < V) {
            float bia = bias[vv];
            #pragma unroll
            for (int mt = 0; mt < 2; mt++) {
                #pragma unroll
                for (int j = 0; j < 4; j++) {
                    int g = mt * 16 + lrowb + j;
                    ob[(size_t)g * V + vv] = acc[ntl][mt][j] + bia;
                }
            }
        }
    }
}

// ---------------------------------------------------------------------------
// K4: log-softmax pieces
// ---------------------------------------------------------------------------
__global__ __launch_bounds__(256) void k_lse_part(const float* __restrict__ out,
                                                  float* __restrict__ part) {
    int bx = blockIdx.x;
    int V, ci, pidx;
    const float* row;
    if (bx < 32 * PG) {
        int g = bx / PG; ci = bx % PG; V = VG;
        row = out + (size_t)g * VG;
        pidx = g * PG + ci;
    } else {
        int b2 = bx - 32 * PG;
        int g = b2 / PS; ci = b2 % PS; V = VS;
        row = out + (size_t)BATCH * VG + (size_t)g * VS;
        pidx = 32 * PG + g * PS + ci;
    }
    int t = threadIdx.x;
    float p = 0.f;
    int base = ci * 2048 + t * 8;
    #pragma unroll
    for (int jj = 0; jj < 8; jj++) {
        int idx = base + jj;
        if (idx < V) p += expf(row[idx]);
    }
    #pragma unroll
    for (int s = 1; s < 64; s <<= 1) p += __shfl_xor(p, s);
    __shared__ float wsum[4];
    if ((t & 63) == 0) wsum[t >> 6] = p;
    __syncthreads();
    if (t == 0) part[pidx] = wsum[0] + wsum[1] + wsum[2] + wsum[3];
}

__global__ __launch_bounds__(64) void k_lse_final(const float* __restrict__ part,
                                                  float* __restrict__ lse) {
    int t = threadIdx.x;
    int head = t >> 5, g = t & 31;
    float s = 0.f;
    if (head == 0) { for (int c = 0; c < PG; c++) s += part[g * PG + c]; }
    else           { for (int c = 0; c < PS; c++) s += part[32 * PG + g * PS + c]; }
    lse[t] = logf(s);
}

__global__ __launch_bounds__(256) void k_sub(float* __restrict__ out,
                                             const float* __restrict__ lse) {
    unsigned i4 = blockIdx.x * 256u + threadIdx.x;
    if (i4 >= 600000u) return;
    unsigned idx = i4 * 4u;
    float l;
    if (idx < 1600000u) l = lse[idx / 50000u];
    else                l = lse[32u + (idx - 1600000u) / 25000u];
    float4 v = *(float4*)(out + idx);
    v.x -= l; v.y -= l; v.z -= l; v.w -= l;
    *(float4*)(out + idx) = v;
}

// ---------------------------------------------------------------------------
extern "C" void kernel_launch(void* const* d_in, const int* in_sizes, int n_in,
                              void* d_out, int out_size, void* d_ws, size_t ws_size,
                              hipStream_t stream) {
    const float* x        = (const float*)d_in[0];
    const int*   ei       = (const int*)  d_in[1];
    const int*   et       = (const int*)  d_in[2];
    const float* basis    = (const float*)d_in[3];
    const float* comp     = (const float*)d_in[4];
    const float* root     = (const float*)d_in[5];
    const float* biasc    = (const float*)d_in[6];
    const float* wg       = (const float*)d_in[7];
    const float* bg       = (const float*)d_in[8];
    const float* wsn      = (const float*)d_in[9];
    const float* bsv      = (const float*)d_in[10];
    float* out = (float*)d_out;

    float* z     = out;
    float* part2 = out + (size_t)BATCH * ZI;
    unsigned* h0t  = (unsigned*)d_ws;            // 8192 uints = 32KB
    float*    plse = (float*)d_ws + 8192;
    float*    lse  = plse + 32 * PG + 32 * PS;

    k_conv     <<<BATCH, 512, 0, stream>>>(x, ei, et, comp, z);
    k_gemm_part<<<NCH * 4, 512, 0, stream>>>(z, root, basis, part2);
    k_h0       <<<BATCH, 256, 0, stream>>>(part2, biasc, h0t);
    k_logits3  <<<GB3 + SB3, 256, 0, stream>>>(h0t, wg, bg, wsn, bsv, out);
    k_lse_part <<<32 * PG + 32 * PS, 256, 0, stream>>>(out, plse);
    k_lse_final<<<1, 64, 0, stream>>>(plse, lse);
    k_sub      <<<2344, 256, 0, stream>>>(out, lse);
}

// Round 4
// 78.333 us; speedup vs baseline: 7.7416x; 1.0573x over previous
//
#include <hip/hip_runtime.h>
#include <hip/hip_bf16.h>

#define BATCH 32
#define NNODE 2048
#define NEDGE 8192
#define DIM   512
#define NREL  8
#define VG    50000
#define VS    25000
#define ZI    4608           // 512 (root) + 8*512 (basis)
#define NCH   36             // 4608 / 128 i-chunks
#define GB3   391            // ceil(50000/128)
#define SB3   196            // ceil(25000/128)
#define PG    25             // lse chunks for global head (2048 each)
#define PS    13             // lse chunks for sense head

typedef __attribute__((ext_vector_type(4))) float f32x4;
typedef __attribute__((ext_vector_type(8))) short s16x8;

// ---------------------------------------------------------------------------
// K1: per-batch edge scan (dst==0 only), builds z[g][0..4607]
// ---------------------------------------------------------------------------
__global__ __launch_bounds__(512) void k_conv(const float* __restrict__ x,
                                              const int* __restrict__ ei,
                                              const int* __restrict__ et,
                                              const float* __restrict__ comp,
                                              float* __restrict__ z) {
    int g = blockIdx.x;
    int t = threadIdx.x;
    int wv = t >> 6, lane = t & 63;
    __shared__ int elds[8 * 128];
    __shared__ int wcnt[8];
    const int* srcp = ei + (size_t)(g * 2 + 0) * NEDGE;
    const int* dstp = ei + (size_t)(g * 2 + 1) * NEDGE;

    int run = 0;
    for (int it = 0; it < 16; it++) {
        int e = wv * 1024 + it * 64 + lane;
        bool m = (dstp[e] == 0);
        unsigned long long mask = __ballot(m);
        int rank = __popcll(mask & ((1ull << lane) - 1ull));
        if (m && (run + rank) < 128) elds[wv * 128 + run + rank] = e;
        run += (int)__popcll(mask);
    }
    if (lane == 0) wcnt[wv] = (run > 128) ? 128 : run;
    __syncthreads();

    int d = t;
    float s0=0,s1=0,s2=0,s3=0,s4=0,s5=0,s6=0,s7=0;
    int   c0=0,c1=0,c2=0,c3=0,c4=0,c5=0,c6=0,c7=0;
    for (int w = 0; w < 8; w++) {
        int cw = wcnt[w];
        for (int i = 0; i < cw; i++) {
            int e = elds[w * 128 + i];
            int r = et[(size_t)g * NEDGE + e];
            int sn = srcp[e];
            float val = x[((size_t)g * NNODE + sn) * DIM + d];
            if (r == 0) { s0 += val; c0++; }
            if (r == 1) { s1 += val; c1++; }
            if (r == 2) { s2 += val; c2++; }
            if (r == 3) { s3 += val; c3++; }
            if (r == 4) { s4 += val; c4++; }
            if (r == 5) { s5 += val; c5++; }
            if (r == 6) { s6 += val; c6++; }
            if (r == 7) { s7 += val; c7++; }
        }
    }
    float sv[8] = {s0,s1,s2,s3,s4,s5,s6,s7};
    float inv[8];
    int   cv[8] = {c0,c1,c2,c3,c4,c5,c6,c7};
    #pragma unroll
    for (int r = 0; r < 8; r++) inv[r] = 1.0f / fmaxf((float)cv[r], 1.0f);

    z[(size_t)g * ZI + d] = x[((size_t)g * NNODE + 0) * DIM + d];
    #pragma unroll
    for (int b = 0; b < 8; b++) {
        float y = 0.f;
        #pragma unroll
        for (int r = 0; r < 8; r++) y += comp[r * 8 + b] * inv[r] * sv[r];
        z[(size_t)g * ZI + 512 + b * 512 + d] = y;
    }
}

// ---------------------------------------------------------------------------
// K2a: partial GEMM  part2[c][g][d] = sum_{i in chunk c} z[g][i] * M[i][d]
// ---------------------------------------------------------------------------
__global__ __launch_bounds__(512) void k_gemm_part(const float* __restrict__ z,
                                                   const float* __restrict__ root,
                                                   const float* __restrict__ basis,
                                                   float* __restrict__ part2) {
    int bx = blockIdx.x;
    int dt = bx & 3;
    int cc = bx >> 2;
    int t = threadIdx.x;
    int dl = t & 127, gq = t >> 7;
    __shared__ float ztT[128][33];
    #pragma unroll
    for (int rep = 0; rep < 8; rep++) {
        int flat = rep * 512 + t;
        int g = flat >> 7, i = flat & 127;
        ztT[i][g] = z[(size_t)g * ZI + cc * 128 + i];
    }
    __syncthreads();
    const float* M = (cc < 4) ? (root + (size_t)(cc * 128) * 512)
                              : (basis + (size_t)((cc - 4) * 128) * 512);
    float acc[8] = {0,0,0,0,0,0,0,0};
    for (int i = 0; i < 128; i++) {
        float m = M[(size_t)i * 512 + dt * 128 + dl];
        #pragma unroll
        for (int j = 0; j < 8; j++) acc[j] += ztT[i][gq * 8 + j] * m;
    }
    #pragma unroll
    for (int j = 0; j < 8; j++) {
        int g = gq * 8 + j;
        part2[((size_t)cc * 32 + g) * 512 + dt * 128 + dl] = acc[j];
    }
}

// ---------------------------------------------------------------------------
// K2b: h0 reduce + relu + pack bf16 pairs.  h0t[g*256 + p] = bf16(2p)|bf16(2p+1)<<16
// ---------------------------------------------------------------------------
__device__ __forceinline__ unsigned bf16rne(float f) {
    unsigned u = __float_as_uint(f);
    return (u + 0x7FFFu + ((u >> 16) & 1u)) >> 16;
}

__global__ __launch_bounds__(256) void k_h0(const float* __restrict__ part2,
                                            const float* __restrict__ bias_conv,
                                            unsigned* __restrict__ h0t) {
    int g = blockIdx.x;
    int p = threadIdx.x;          // pair index kp = 0..255
    int d0 = 2 * p;
    float v0 = bias_conv[d0], v1 = bias_conv[d0 + 1];
    for (int cc = 0; cc < NCH; cc++) {
        const float* pp = part2 + ((size_t)cc * 32 + g) * 512 + d0;
        v0 += pp[0];
        v1 += pp[1];
    }
    v0 = fmaxf(v0, 0.f);
    v1 = fmaxf(v1, 0.f);
    h0t[g * 256 + p] = bf16rne(v0) | (bf16rne(v1) << 16);
}

// ---------------------------------------------------------------------------
// K3 (MFMA, pipelined): logits[g][v] = bias[v] + dot(h0[g], w[v]).
// 128 vocab rows/block, 16 K-chunks of 32 k (16KB fp32 each).
// THREE W buffers + counted vmcnt + raw s_barrier: chunk c+1 stays in
// flight across the barrier (T3/T4); issue of c+2 happens AFTER compute
// of c, so the 3-buffer rotation is race-free with one barrier per iter.
// All LDS accesses 16B-granule XOR-swizzled by (row&7) -> ~conflict-free.
// LDS: 32KB h0 + 3x16KB W = 80KB -> 2 blocks/CU.
// ---------------------------------------------------------------------------
__device__ __forceinline__ void gload_lds16(const float* gsrc, float* ldst) {
    __builtin_amdgcn_global_load_lds(
        (const __attribute__((address_space(1))) void*)gsrc,
        (__attribute__((address_space(3))) void*)ldst,
        16, 0, 0);
}

__device__ __forceinline__ short f2bf(float f) {
    __hip_bfloat16 h = __float2bfloat16(f);
    return *reinterpret_cast<short*>(&h);
}

__global__ __launch_bounds__(256, 2) void k_logits4(const unsigned* __restrict__ h0t,
                                                    const float* __restrict__ wg,
                                                    const float* __restrict__ bg,
                                                    const float* __restrict__ wsn,
                                                    const float* __restrict__ bsv,
                                                    float* __restrict__ out) {
    __shared__ __align__(16) unsigned char hlds[32768];      // h0 [32 g][1KB], 16B-XOR
    __shared__ __align__(16) unsigned char wlds[3][16384];   // W  [128 r][128B], 16B-XOR

    int t = threadIdx.x;
    int bx = blockIdx.x;
    int wv = t >> 6, l = t & 63;

    const float* w; const float* bias; float* ob; int V; int v0;
    if (bx < GB3) { w = wg;  bias = bg;  ob = out;                      V = VG; v0 = bx * 128; }
    else          { w = wsn; bias = bsv; ob = out + (size_t)BATCH * VG; V = VS; v0 = (bx - GB3) * 128; }
    int Vm1 = V - 1;

    // ---- prologue: read h0, issue W chunks 0 & 1, write h0 -> LDS ----
    uint4 hv[8];
    #pragma unroll
    for (int rep = 0; rep < 8; rep++)
        hv[rep] = *(const uint4*)&h0t[(rep * 256 + t) * 4];

    #pragma unroll
    for (int kc0 = 0; kc0 < 2; kc0++) {
        #pragma unroll
        for (int i = 0; i < 4; i++) {
            int o = i * 256 + t;               // 16B granule 0..1023
            int row = o >> 3, gq = o & 7;
            int vr = v0 + row; if (vr > Vm1) vr = Vm1;
            const float* src = w + (size_t)vr * 512 + kc0 * 32
                             + ((gq ^ (row & 7)) << 2);
            gload_lds16(src, (float*)&wlds[kc0][o * 16]);
        }
    }

    #pragma unroll
    for (int rep = 0; rep < 8; rep++) {
        int idx = rep * 256 + t;
        int g = idx >> 6, q = idx & 63;        // q = 16B granule in 1KB row
        *(uint4*)&hlds[g * 1024 + ((q ^ (g & 7)) << 4)] = hv[rep];
    }
    asm volatile("s_waitcnt lgkmcnt(0)" ::: "memory");

    f32x4 acc[2][2];
    #pragma unroll
    for (int a = 0; a < 2; a++)
        #pragma unroll
        for (int b = 0; b < 2; b++) acc[a][b] = (f32x4){0.f, 0.f, 0.f, 0.f};

    int g32 = l >> 4;                      // k-quarter 0..3
    int gl  = l & 15;
    int axor = (gl & 7) << 4;

    for (int kc = 0; kc < 16; kc++) {
        if (kc == 0 || kc == 15) { asm volatile("s_waitcnt vmcnt(0)" ::: "memory"); }
        else                     { asm volatile("s_waitcnt vmcnt(4)" ::: "memory"); }
        __builtin_amdgcn_s_barrier();

        const unsigned char* wb = wlds[kc % 3];
        int abase = kc * 64 + g32 * 16;
        s16x8 a0 = *(const s16x8*)&hlds[gl * 1024 + (abase ^ axor)];
        s16x8 a1 = *(const s16x8*)&hlds[(gl + 16) * 1024 + (abase ^ axor)];

        #pragma unroll
        for (int ntl = 0; ntl < 2; ntl++) {
            int rloc = (wv * 2 + ntl) * 16 + gl;
            int s = rloc & 7;
            float4 blo = *(const float4*)&wb[rloc * 128 + (((g32 * 2)     ^ s) << 4)];
            float4 bhi = *(const float4*)&wb[rloc * 128 + (((g32 * 2 + 1) ^ s) << 4)];
            s16x8 bf;
            bf[0] = f2bf(blo.x); bf[1] = f2bf(blo.y);
            bf[2] = f2bf(blo.z); bf[3] = f2bf(blo.w);
            bf[4] = f2bf(bhi.x); bf[5] = f2bf(bhi.y);
            bf[6] = f2bf(bhi.z); bf[7] = f2bf(bhi.w);
            acc[ntl][0] = __builtin_amdgcn_mfma_f32_16x16x32_bf16(a0, bf, acc[ntl][0], 0, 0, 0);
            acc[ntl][1] = __builtin_amdgcn_mfma_f32_16x16x32_bf16(a1, bf, acc[ntl][1], 0, 0, 0);
        }

        if (kc + 2 < 16) {                 // issue AFTER compute (3-buf safety)
            #pragma unroll
            for (int i = 0; i < 4; i++) {
                int o = i * 256 + t;
                int row = o >> 3, gq = o & 7;
                int vr = v0 + row; if (vr > Vm1) vr = Vm1;
                const float* src = w + (size_t)vr * 512 + (kc + 2) * 32
                                 + ((gq ^ (row & 7)) << 2);
                gload_lds16(src, (float*)&wlds[(kc + 2) % 3][o * 16]);
            }
        }
    }

    // ---- epilogue: C/D layout col=lane&15, row=(lane>>4)*4+j ----
    int lrowb = (l >> 4) * 4;
    #pragma unroll
    for (int ntl = 0; ntl < 2; ntl++) {
        int vv = v0 + (wv * 2 + ntl) * 16 + gl;
        if (vv < V) {
            float bia = bias[vv];
            #pragma unroll
            for (int mt = 0; mt < 2; mt++) {
                #pragma unroll
                for (int j = 0; j < 4; j++) {
                    int g = mt * 16 + lrowb + j;
                    ob[(size_t)g * V + vv] = acc[ntl][mt][j] + bia;
                }
            }
        }
    }
}

// ---------------------------------------------------------------------------
// K4: log-softmax pieces
// ---------------------------------------------------------------------------
__global__ __launch_bounds__(256) void k_lse_part(const float* __restrict__ out,
                                                  float* __restrict__ part) {
    int bx = blockIdx.x;
    int V, ci, pidx;
    const float* row;
    if (bx < 32 * PG) {
        int g = bx / PG; ci = bx % PG; V = VG;
        row = out + (size_t)g * VG;
        pidx = g * PG + ci;
    } else {
        int b2 = bx - 32 * PG;
        int g = b2 / PS; ci = b2 % PS; V = VS;
        row = out + (size_t)BATCH * VG + (size_t)g * VS;
        pidx = 32 * PG + g * PS + ci;
    }
    int t = threadIdx.x;
    float p = 0.f;
    int base = ci * 2048 + t * 8;
    #pragma unroll
    for (int jj = 0; jj < 8; jj++) {
        int idx = base + jj;
        if (idx < V) p += expf(row[idx]);
    }
    #pragma unroll
    for (int s = 1; s < 64; s <<= 1) p += __shfl_xor(p, s);
    __shared__ float wsum[4];
    if ((t & 63) == 0) wsum[t >> 6] = p;
    __syncthreads();
    if (t == 0) part[pidx] = wsum[0] + wsum[1] + wsum[2] + wsum[3];
}

__global__ __launch_bounds__(64) void k_lse_final(const float* __restrict__ part,
                                                  float* __restrict__ lse) {
    int t = threadIdx.x;
    int head = t >> 5, g = t & 31;
    float s = 0.f;
    if (head == 0) { for (int c = 0; c < PG; c++) s += part[g * PG + c]; }
    else           { for (int c = 0; c < PS; c++) s += part[32 * PG + g * PS + c]; }
    lse[t] = logf(s);
}

__global__ __launch_bounds__(256) void k_sub(float* __restrict__ out,
                                             const float* __restrict__ lse) {
    unsigned i4 = blockIdx.x * 256u + threadIdx.x;
    if (i4 >= 600000u) return;
    unsigned idx = i4 * 4u;
    float l;
    if (idx < 1600000u) l = lse[idx / 50000u];
    else                l = lse[32u + (idx - 1600000u) / 25000u];
    float4 v = *(float4*)(out + idx);
    v.x -= l; v.y -= l; v.z -= l; v.w -= l;
    *(float4*)(out + idx) = v;
}

// ---------------------------------------------------------------------------
extern "C" void kernel_launch(void* const* d_in, const int* in_sizes, int n_in,
                              void* d_out, int out_size, void* d_ws, size_t ws_size,
                              hipStream_t stream) {
    const float* x        = (const float*)d_in[0];
    const int*   ei       = (const int*)  d_in[1];
    const int*   et       = (const int*)  d_in[2];
    const float* basis    = (const float*)d_in[3];
    const float* comp     = (const float*)d_in[4];
    const float* root     = (const float*)d_in[5];
    const float* biasc    = (const float*)d_in[6];
    const float* wg       = (const float*)d_in[7];
    const float* bg       = (const float*)d_in[8];
    const float* wsn      = (const float*)d_in[9];
    const float* bsv      = (const float*)d_in[10];
    float* out = (float*)d_out;

    float* z     = out;
    float* part2 = out + (size_t)BATCH * ZI;
    unsigned* h0t  = (unsigned*)d_ws;            // 8192 uints = 32KB
    float*    plse = (float*)d_ws + 8192;
    float*    lse  = plse + 32 * PG + 32 * PS;

    k_conv     <<<BATCH, 512, 0, stream>>>(x, ei, et, comp, z);
    k_gemm_part<<<NCH * 4, 512, 0, stream>>>(z, root, basis, part2);
    k_h0       <<<BATCH, 256, 0, stream>>>(part2, biasc, h0t);
    k_logits4  <<<GB3 + SB3, 256, 0, stream>>>(h0t, wg, bg, wsn, bsv, out);
    k_lse_part <<<32 * PG + 32 * PS, 256, 0, stream>>>(out, plse);
    k_lse_final<<<1, 64, 0, stream>>>(plse, lse);
    k_sub      <<<2344, 256, 0, stream>>>(out, lse);
}

// Round 5
// 77.792 us; speedup vs baseline: 7.7954x; 1.0070x over previous
//
#include <hip/hip_runtime.h>
#include <hip/hip_bf16.h>

#define BATCH 32
#define NNODE 2048
#define NEDGE 8192
#define DIM   512
#define NREL  8
#define VG    50000
#define VS    25000
#define ZI    4608           // 512 (root) + 8*512 (basis)
#define NCH   36             // 4608 / 128 i-chunks
#define GB5   782            // ceil(50000/64)
#define SB5   391            // ceil(25000/64)
#define PG    25             // lse chunks for global head (2048 each)
#define PS    13             // lse chunks for sense head

typedef __attribute__((ext_vector_type(4))) float f32x4;
typedef __attribute__((ext_vector_type(8))) short s16x8;

// ---------------------------------------------------------------------------
// K1: per-batch edge scan (dst==0 only), builds z[g][0..4607]
// ---------------------------------------------------------------------------
__global__ __launch_bounds__(512) void k_conv(const float* __restrict__ x,
                                              const int* __restrict__ ei,
                                              const int* __restrict__ et,
                                              const float* __restrict__ comp,
                                              float* __restrict__ z) {
    int g = blockIdx.x;
    int t = threadIdx.x;
    int wv = t >> 6, lane = t & 63;
    __shared__ int elds[8 * 128];
    __shared__ int wcnt[8];
    const int* srcp = ei + (size_t)(g * 2 + 0) * NEDGE;
    const int* dstp = ei + (size_t)(g * 2 + 1) * NEDGE;

    int run = 0;
    for (int it = 0; it < 16; it++) {
        int e = wv * 1024 + it * 64 + lane;
        bool m = (dstp[e] == 0);
        unsigned long long mask = __ballot(m);
        int rank = __popcll(mask & ((1ull << lane) - 1ull));
        if (m && (run + rank) < 128) elds[wv * 128 + run + rank] = e;
        run += (int)__popcll(mask);
    }
    if (lane == 0) wcnt[wv] = (run > 128) ? 128 : run;
    __syncthreads();

    int d = t;
    float s0=0,s1=0,s2=0,s3=0,s4=0,s5=0,s6=0,s7=0;
    int   c0=0,c1=0,c2=0,c3=0,c4=0,c5=0,c6=0,c7=0;
    for (int w = 0; w < 8; w++) {
        int cw = wcnt[w];
        for (int i = 0; i < cw; i++) {
            int e = elds[w * 128 + i];
            int r = et[(size_t)g * NEDGE + e];
            int sn = srcp[e];
            float val = x[((size_t)g * NNODE + sn) * DIM + d];
            if (r == 0) { s0 += val; c0++; }
            if (r == 1) { s1 += val; c1++; }
            if (r == 2) { s2 += val; c2++; }
            if (r == 3) { s3 += val; c3++; }
            if (r == 4) { s4 += val; c4++; }
            if (r == 5) { s5 += val; c5++; }
            if (r == 6) { s6 += val; c6++; }
            if (r == 7) { s7 += val; c7++; }
        }
    }
    float sv[8] = {s0,s1,s2,s3,s4,s5,s6,s7};
    float inv[8];
    int   cv[8] = {c0,c1,c2,c3,c4,c5,c6,c7};
    #pragma unroll
    for (int r = 0; r < 8; r++) inv[r] = 1.0f / fmaxf((float)cv[r], 1.0f);

    z[(size_t)g * ZI + d] = x[((size_t)g * NNODE + 0) * DIM + d];
    #pragma unroll
    for (int b = 0; b < 8; b++) {
        float y = 0.f;
        #pragma unroll
        for (int r = 0; r < 8; r++) y += comp[r * 8 + b] * inv[r] * sv[r];
        z[(size_t)g * ZI + 512 + b * 512 + d] = y;
    }
}

// ---------------------------------------------------------------------------
// K2a: partial GEMM  part2[c][g][d] = sum_{i in chunk c} z[g][i] * M[i][d]
// ---------------------------------------------------------------------------
__global__ __launch_bounds__(512) void k_gemm_part(const float* __restrict__ z,
                                                   const float* __restrict__ root,
                                                   const float* __restrict__ basis,
                                                   float* __restrict__ part2) {
    int bx = blockIdx.x;
    int dt = bx & 3;
    int cc = bx >> 2;
    int t = threadIdx.x;
    int dl = t & 127, gq = t >> 7;
    __shared__ float ztT[128][33];
    #pragma unroll
    for (int rep = 0; rep < 8; rep++) {
        int flat = rep * 512 + t;
        int g = flat >> 7, i = flat & 127;
        ztT[i][g] = z[(size_t)g * ZI + cc * 128 + i];
    }
    __syncthreads();
    const float* M = (cc < 4) ? (root + (size_t)(cc * 128) * 512)
                              : (basis + (size_t)((cc - 4) * 128) * 512);
    float acc[8] = {0,0,0,0,0,0,0,0};
    for (int i = 0; i < 128; i++) {
        float m = M[(size_t)i * 512 + dt * 128 + dl];
        #pragma unroll
        for (int j = 0; j < 8; j++) acc[j] += ztT[i][gq * 8 + j] * m;
    }
    #pragma unroll
    for (int j = 0; j < 8; j++) {
        int g = gq * 8 + j;
        part2[((size_t)cc * 32 + g) * 512 + dt * 128 + dl] = acc[j];
    }
}

// ---------------------------------------------------------------------------
// K2b: h0 reduce + relu + pack bf16 pairs.  h0t[g*256 + p] = bf16(2p)|bf16(2p+1)<<16
// ---------------------------------------------------------------------------
__device__ __forceinline__ unsigned bf16rne(float f) {
    unsigned u = __float_as_uint(f);
    return (u + 0x7FFFu + ((u >> 16) & 1u)) >> 16;
}

__global__ __launch_bounds__(256) void k_h0(const float* __restrict__ part2,
                                            const float* __restrict__ bias_conv,
                                            unsigned* __restrict__ h0t) {
    int g = blockIdx.x;
    int p = threadIdx.x;          // pair index kp = 0..255
    int d0 = 2 * p;
    float v0 = bias_conv[d0], v1 = bias_conv[d0 + 1];
    for (int cc = 0; cc < NCH; cc++) {
        const float* pp = part2 + ((size_t)cc * 32 + g) * 512 + d0;
        v0 += pp[0];
        v1 += pp[1];
    }
    v0 = fmaxf(v0, 0.f);
    v1 = fmaxf(v1, 0.f);
    h0t[g * 256 + p] = bf16rne(v0) | (bf16rne(v1) << 16);
}

// ---------------------------------------------------------------------------
// K3 (barrier-free streaming MFMA GEMV): logits[g][v] = bias[v] + dot(h0[g], w[v]).
// Each wave owns 16 vocab rows (B-cols). Lane l loads EXACTLY its B-fragment
// (row l&15, k-slice (l>>4)*8, 2xfloat4 = 32B/chunk) global->VGPR. No W LDS,
// no barriers in the main loop: full 16-chunk unroll, compiler emits counted
// vmcnt. h0 (A-fragments) in 32KB XOR-swizzled LDS, loaded once.
// LDS 32KB + VGPR<=128 -> 4 blocks/CU = 16 waves/CU -> deep MLP.
// ---------------------------------------------------------------------------
__device__ __forceinline__ short f2bf(float f) {
    __hip_bfloat16 h = __float2bfloat16(f);
    return *reinterpret_cast<short*>(&h);
}

__global__ __launch_bounds__(256, 4) void k_logits5(const unsigned* __restrict__ h0t,
                                                    const float* __restrict__ wg,
                                                    const float* __restrict__ bg,
                                                    const float* __restrict__ wsn,
                                                    const float* __restrict__ bsv,
                                                    float* __restrict__ out) {
    __shared__ __align__(16) unsigned char hlds[32768];   // h0 [32 g][1KB], 16B-XOR

    int t = threadIdx.x;
    int bx = blockIdx.x;
    int wv = t >> 6, l = t & 63;

    const float* w; const float* bias; float* ob; int V; int v0;
    if (bx < GB5) { w = wg;  bias = bg;  ob = out;                      V = VG; v0 = bx * 64; }
    else          { w = wsn; bias = bsv; ob = out + (size_t)BATCH * VG; V = VS; v0 = (bx - GB5) * 64; }

    // ---- h0 -> LDS (16B-granule XOR by batch row) ----
    #pragma unroll
    for (int rep = 0; rep < 8; rep++) {
        int idx = rep * 256 + t;               // uint4 index, 2048 total
        int g = idx >> 6, q = idx & 63;        // q = 16B granule in 1KB row
        uint4 val = *(const uint4*)&h0t[idx * 4];
        *(uint4*)&hlds[g * 1024 + ((q ^ (g & 7)) << 4)] = val;
    }
    __syncthreads();

    int c  = l & 15;          // vocab-col within wave tile AND h0 batch row
    int kg = l >> 4;          // k-group 0..3
    int vb = v0 + wv * 16 + c;
    int vr = (vb < V) ? vb : (V - 1);
    const float4* __restrict__ wrow = (const float4*)(w + (size_t)vr * 512);  // 128 f4
    int swz = c & 7;
    const unsigned char* ha = &hlds[c * 1024];
    const unsigned char* hb = &hlds[(c + 16) * 1024];

    f32x4 acc0 = {0.f, 0.f, 0.f, 0.f};
    f32x4 acc1 = {0.f, 0.f, 0.f, 0.f};

    #pragma unroll
    for (int kc = 0; kc < 16; kc++) {
        float4 b0 = wrow[kc * 8 + kg * 2];
        float4 b1 = wrow[kc * 8 + kg * 2 + 1];
        int gr = ((kc * 4 + kg) ^ swz) << 4;
        s16x8 a0 = *(const s16x8*)(ha + gr);
        s16x8 a1 = *(const s16x8*)(hb + gr);
        s16x8 bf;
        bf[0] = f2bf(b0.x); bf[1] = f2bf(b0.y); bf[2] = f2bf(b0.z); bf[3] = f2bf(b0.w);
        bf[4] = f2bf(b1.x); bf[5] = f2bf(b1.y); bf[6] = f2bf(b1.z); bf[7] = f2bf(b1.w);
        acc0 = __builtin_amdgcn_mfma_f32_16x16x32_bf16(a0, bf, acc0, 0, 0, 0);
        acc1 = __builtin_amdgcn_mfma_f32_16x16x32_bf16(a1, bf, acc1, 0, 0, 0);
    }

    // C/D layout: col = lane&15 (vocab), row = (lane>>4)*4 + j (batch)
    if (vb < V) {
        float bia = bias[vb];
        #pragma unroll
        for (int j = 0; j < 4; j++) {
            int g0 = kg * 4 + j;
            ob[(size_t)g0 * V + vb]        = acc0[j] + bia;
            ob[(size_t)(g0 + 16) * V + vb] = acc1[j] + bia;
        }
    }
}

// ---------------------------------------------------------------------------
// K4: log-softmax pieces
// ---------------------------------------------------------------------------
__global__ __launch_bounds__(256) void k_lse_part(const float* __restrict__ out,
                                                  float* __restrict__ part) {
    int bx = blockIdx.x;
    int V, ci, pidx;
    const float* row;
    if (bx < 32 * PG) {
        int g = bx / PG; ci = bx % PG; V = VG;
        row = out + (size_t)g * VG;
        pidx = g * PG + ci;
    } else {
        int b2 = bx - 32 * PG;
        int g = b2 / PS; ci = b2 % PS; V = VS;
        row = out + (size_t)BATCH * VG + (size_t)g * VS;
        pidx = 32 * PG + g * PS + ci;
    }
    int t = threadIdx.x;
    float p = 0.f;
    int base = ci * 2048 + t * 8;
    #pragma unroll
    for (int jj = 0; jj < 8; jj++) {
        int idx = base + jj;
        if (idx < V) p += expf(row[idx]);
    }
    #pragma unroll
    for (int s = 1; s < 64; s <<= 1) p += __shfl_xor(p, s);
    __shared__ float wsum[4];
    if ((t & 63) == 0) wsum[t >> 6] = p;
    __syncthreads();
    if (t == 0) part[pidx] = wsum[0] + wsum[1] + wsum[2] + wsum[3];
}

__global__ __launch_bounds__(64) void k_lse_final(const float* __restrict__ part,
                                                  float* __restrict__ lse) {
    int t = threadIdx.x;
    int head = t >> 5, g = t & 31;
    float s = 0.f;
    if (head == 0) { for (int c = 0; c < PG; c++) s += part[g * PG + c]; }
    else           { for (int c = 0; c < PS; c++) s += part[32 * PG + g * PS + c]; }
    lse[t] = logf(s);
}

__global__ __launch_bounds__(256) void k_sub(float* __restrict__ out,
                                             const float* __restrict__ lse) {
    unsigned i4 = blockIdx.x * 256u + threadIdx.x;
    if (i4 >= 600000u) return;
    unsigned idx = i4 * 4u;
    float l;
    if (idx < 1600000u) l = lse[idx / 50000u];
    else                l = lse[32u + (idx - 1600000u) / 25000u];
    float4 v = *(float4*)(out + idx);
    v.x -= l; v.y -= l; v.z -= l; v.w -= l;
    *(float4*)(out + idx) = v;
}

// ---------------------------------------------------------------------------
extern "C" void kernel_launch(void* const* d_in, const int* in_sizes, int n_in,
                              void* d_out, int out_size, void* d_ws, size_t ws_size,
                              hipStream_t stream) {
    const float* x        = (const float*)d_in[0];
    const int*   ei       = (const int*)  d_in[1];
    const int*   et       = (const int*)  d_in[2];
    const float* basis    = (const float*)d_in[3];
    const float* comp     = (const float*)d_in[4];
    const float* root     = (const float*)d_in[5];
    const float* biasc    = (const float*)d_in[6];
    const float* wg       = (const float*)d_in[7];
    const float* bg       = (const float*)d_in[8];
    const float* wsn      = (const float*)d_in[9];
    const float* bsv      = (const float*)d_in[10];
    float* out = (float*)d_out;

    float* z     = out;
    float* part2 = out + (size_t)BATCH * ZI;
    unsigned* h0t  = (unsigned*)d_ws;            // 8192 uints = 32KB
    float*    plse = (float*)d_ws + 8192;
    float*    lse  = plse + 32 * PG + 32 * PS;

    k_conv     <<<BATCH, 512, 0, stream>>>(x, ei, et, comp, z);
    k_gemm_part<<<NCH * 4, 512, 0, stream>>>(z, root, basis, part2);
    k_h0       <<<BATCH, 256, 0, stream>>>(part2, biasc, h0t);
    k_logits5  <<<GB5 + SB5, 256, 0, stream>>>(h0t, wg, bg, wsn, bsv, out);
    k_lse_part <<<32 * PG + 32 * PS, 256, 0, stream>>>(out, plse);
    k_lse_final<<<1, 64, 0, stream>>>(plse, lse);
    k_sub      <<<2344, 256, 0, stream>>>(out, lse);
}